// Round 1
// baseline (644.648 us; speedup 1.0000x reference)
//
#include <hip/hip_runtime.h>
#include <math.h>

// Workspace layout (floats)
#define WS_FLAT 0                      // 65536   pooled+flattened p4
#define WS_PART 65536                  // 524288  gemm1 split-K partials (256 x 2048)
#define WS_H1   (65536 + 524288)       // 2048
#define WS_H2   (WS_H1 + 2048)         // 4096
#define WS_POLY (WS_H2 + 4096)         // 8000    current polygons [4][20][50][2]

// ---------------- Kernel 1: AdaptiveAvgPool2d(8) on p4 [4,256,64,64] -> flat [4,16384]
__global__ void pool_k(const float* __restrict__ p4, float* __restrict__ flat) {
    int o = blockIdx.x * blockDim.x + threadIdx.x;   // 65536 outputs
    int b = o >> 14;
    int c = (o >> 6) & 255;
    int ij = o & 63;
    int i = ij >> 3, j = ij & 7;
    const float* base = p4 + (((size_t)(b * 256 + c) * 64 + i * 8) * 64 + j * 8);
    float s = 0.f;
    #pragma unroll
    for (int u = 0; u < 8; ++u) {
        const float4* r = (const float4*)(base + u * 64);
        float4 a = r[0], bb = r[1];
        s += a.x + a.y + a.z + a.w + bb.x + bb.y + bb.z + bb.w;
    }
    flat[o] = s * (1.0f / 64.0f);
}

// ---------------- Kernel 2a: GEMM1 split-K: flat[4,16384] @ iw1[16384,512] -> partials
// grid 256 (k-chunks of 64), block 512 (one column each)
__global__ void g1a_k(const float* __restrict__ flat, const float* __restrict__ iw1,
                      float* __restrict__ part) {
    __shared__ float sf[4][64];
    int tid = threadIdx.x;              // 0..511
    int kbase = blockIdx.x * 64;
    if (tid < 256) sf[tid >> 6][tid & 63] = flat[(tid >> 6) * 16384 + kbase + (tid & 63)];
    __syncthreads();
    float a0 = 0.f, a1 = 0.f, a2 = 0.f, a3 = 0.f;
    for (int k = 0; k < 64; ++k) {
        float w = iw1[(size_t)(kbase + k) * 512 + tid];
        a0 = fmaf(sf[0][k], w, a0);
        a1 = fmaf(sf[1][k], w, a1);
        a2 = fmaf(sf[2][k], w, a2);
        a3 = fmaf(sf[3][k], w, a3);
    }
    float* pp = part + (size_t)blockIdx.x * 2048;
    pp[tid] = a0; pp[512 + tid] = a1; pp[1024 + tid] = a2; pp[1536 + tid] = a3;
}

// ---------------- Kernel 2b: reduce 256 partials -> h1[2048] (+bias, relu)
// grid 64, block 256 = 8 c-lanes x 32 outputs
__global__ void g1b_k(const float* __restrict__ part, const float* __restrict__ ib1,
                      float* __restrict__ h1) {
    __shared__ float red[8][32];
    int tid = threadIdx.x;
    int cc = tid >> 5, oo = tid & 31;
    int o = blockIdx.x * 32 + oo;
    float s = 0.f;
    for (int i = 0; i < 32; ++i)
        s += part[(size_t)(cc + 8 * i) * 2048 + o];
    red[cc][oo] = s;
    __syncthreads();
    if (cc == 0) {
        float t = 0.f;
        #pragma unroll
        for (int c2 = 0; c2 < 8; ++c2) t += red[c2][oo];
        t += ib1[o & 511];
        h1[o] = fmaxf(t, 0.f);
    }
}

// ---------------- Kernel 3: GEMM2 h1[4,512] @ iw2[512,1024] -> h2[4,1024] (relu)
// grid 16 = 4 b x 4 j-tiles, block 256
__global__ void g2_k(const float* __restrict__ h1, const float* __restrict__ iw2,
                     const float* __restrict__ ib2, float* __restrict__ h2) {
    __shared__ float sh[512];
    int tid = threadIdx.x;
    int b = blockIdx.x >> 2, jt = blockIdx.x & 3;
    sh[tid] = h1[b * 512 + tid];
    sh[tid + 256] = h1[b * 512 + 256 + tid];
    __syncthreads();
    int j = jt * 256 + tid;
    float acc = ib2[j];
    for (int k = 0; k < 512; ++k)
        acc = fmaf(sh[k], iw2[(size_t)k * 1024 + j], acc);
    h2[b * 1024 + j] = fmaxf(acc, 0.f);
}

// ---------------- Kernel 4: GEMM3 h2[4,1024] @ iw3[1024,2000] -> sigmoid -> init polys
__global__ void g3_k(const float* __restrict__ h2, const float* __restrict__ iw3,
                     const float* __restrict__ ib3, float* __restrict__ out_init,
                     float* __restrict__ poly) {
    int o = blockIdx.x * 256 + threadIdx.x;
    if (o >= 8000) return;
    int b = o / 2000, j = o % 2000;
    const float* h = h2 + b * 1024;
    float acc = ib3[j];
    for (int k = 0; k < 1024; ++k)
        acc = fmaf(h[k], iw3[(size_t)k * 2000 + j], acc);
    float s = 1.f / (1.f + expf(-acc));
    out_init[o] = s;   // d_out init_polygons region
    poly[o] = s;       // working polygons
}

// ---------------- Kernel 5: one refinement step (sample + MLP + update), 8 pts/block
__global__ void __launch_bounds__(256) step_k(
    const float* __restrict__ p2,
    const float* __restrict__ rw1, const float* __restrict__ rb1,
    const float* __restrict__ rw2, const float* __restrict__ rb2,
    const float* __restrict__ rw3, const float* __restrict__ rb3,
    float* __restrict__ poly) {
    __shared__ __align__(16) float s_inp[258 * 8];  // [k][p]
    __shared__ __align__(16) float s_r1[256 * 8];   // [j][p]
    __shared__ __align__(16) float s_r2[128 * 8];   // [j][p]
    int tid = threadIdx.x;
    int pt0 = blockIdx.x * 8;

    // Phase A: bilinear border sampling, channel = tid, 8 points
    float val[8];
    #pragma unroll
    for (int pp = 0; pp < 8; ++pp) {
        int pt = pt0 + pp;
        int b = pt / 1000;
        float cx = poly[pt * 2], cy = poly[pt * 2 + 1];
        float ix = fminf(fmaxf(cx * 256.f - 0.5f, 0.f), 255.f);
        float iy = fminf(fmaxf(cy * 256.f - 0.5f, 0.f), 255.f);
        float x0f = floorf(ix), y0f = floorf(iy);
        int x0 = (int)x0f, y0 = (int)y0f;
        int x1 = min(x0 + 1, 255), y1 = min(y0 + 1, 255);
        float wx = ix - x0f, wy = iy - y0f;
        const float* fb = p2 + ((size_t)(b * 256 + tid) << 16);
        float f00 = fb[(y0 << 8) + x0], f01 = fb[(y0 << 8) + x1];
        float f10 = fb[(y1 << 8) + x0], f11 = fb[(y1 << 8) + x1];
        float top = f00 * (1.f - wx) + f01 * wx;
        float bot = f10 * (1.f - wx) + f11 * wx;
        val[pp] = top * (1.f - wy) + bot * wy;
    }
    ((float4*)&s_inp[tid * 8])[0] = make_float4(val[0], val[1], val[2], val[3]);
    ((float4*)&s_inp[tid * 8])[1] = make_float4(val[4], val[5], val[6], val[7]);
    if (tid < 16) {  // coords rows 256,257 of inp
        int p = tid >> 1, d = tid & 1;
        s_inp[(256 + d) * 8 + p] = poly[(pt0 + p) * 2 + d];
    }
    __syncthreads();

    // r1 = relu(inp @ rw1 + rb1): thread = column j, 8 accumulators (one/point)
    {
        float bias = rb1[tid];
        float a0 = bias, a1 = bias, a2 = bias, a3 = bias;
        float a4 = bias, a5 = bias, a6 = bias, a7 = bias;
        for (int k = 0; k < 258; ++k) {
            float w = rw1[k * 256 + tid];
            float4 v0 = ((const float4*)&s_inp[k * 8])[0];
            float4 v1 = ((const float4*)&s_inp[k * 8])[1];
            a0 = fmaf(v0.x, w, a0); a1 = fmaf(v0.y, w, a1);
            a2 = fmaf(v0.z, w, a2); a3 = fmaf(v0.w, w, a3);
            a4 = fmaf(v1.x, w, a4); a5 = fmaf(v1.y, w, a5);
            a6 = fmaf(v1.z, w, a6); a7 = fmaf(v1.w, w, a7);
        }
        ((float4*)&s_r1[tid * 8])[0] =
            make_float4(fmaxf(a0, 0.f), fmaxf(a1, 0.f), fmaxf(a2, 0.f), fmaxf(a3, 0.f));
        ((float4*)&s_r1[tid * 8])[1] =
            make_float4(fmaxf(a4, 0.f), fmaxf(a5, 0.f), fmaxf(a6, 0.f), fmaxf(a7, 0.f));
    }
    __syncthreads();

    // r2 = relu(r1 @ rw2 + rb2): thread = (column j in [0,128), point-half ph)
    {
        int j = tid & 127, ph = tid >> 7;
        float bias = rb2[j];
        float c0 = bias, c1 = bias, c2 = bias, c3 = bias;
        for (int k = 0; k < 256; ++k) {
            float w = rw2[k * 128 + j];
            float4 v = ((const float4*)&s_r1[k * 8])[ph];
            c0 = fmaf(v.x, w, c0); c1 = fmaf(v.y, w, c1);
            c2 = fmaf(v.z, w, c2); c3 = fmaf(v.w, w, c3);
        }
        ((float4*)&s_r2[j * 8])[ph] =
            make_float4(fmaxf(c0, 0.f), fmaxf(c1, 0.f), fmaxf(c2, 0.f), fmaxf(c3, 0.f));
    }
    __syncthreads();

    // r3 -> tanh -> scaled clip -> polygon update (16 outputs: 8 pts x 2 dims)
    if (tid < 16) {
        int p = tid >> 1, d = tid & 1;
        float acc = rb3[d];
        for (int k = 0; k < 128; ++k)
            acc = fmaf(s_r2[k * 8 + p], rw3[k * 2 + d], acc);
        float disp = tanhf(acc) * 0.08f;
        disp = fminf(fmaxf(disp, -0.16f), 0.16f);
        int idx = (pt0 + p) * 2 + d;
        float nv = poly[idx] + disp;
        poly[idx] = fminf(fmaxf(nv, 0.f), 1.f);
    }
}

// ---------------- Kernel 6: validity head + final polygon copy to d_out
__global__ void valid_k(const float* __restrict__ poly,
                        const float* __restrict__ vw1, const float* __restrict__ vb1,
                        const float* __restrict__ vw2, const float* __restrict__ vb2,
                        float* __restrict__ out) {
    __shared__ float sp[100];
    __shared__ float sred[2];
    int tid = threadIdx.x;  // 128
    int row = blockIdx.x;   // 80
    if (tid < 100) {
        float v = poly[row * 100 + tid];
        sp[tid] = v;
        out[row * 100 + tid] = v;   // polygons output copy
    }
    __syncthreads();
    float acc = vb1[tid];
    for (int k = 0; k < 100; ++k)
        acc = fmaf(sp[k], vw1[k * 128 + tid], acc);
    float pr = fmaxf(acc, 0.f) * vw2[tid];
    #pragma unroll
    for (int off = 32; off > 0; off >>= 1)
        pr += __shfl_down(pr, off, 64);
    if ((tid & 63) == 0) sred[tid >> 6] = pr;
    __syncthreads();
    if (tid == 0) {
        float s = sred[0] + sred[1] + vb2[0];
        out[8000 + row] = 1.f / (1.f + expf(-s));
    }
}

extern "C" void kernel_launch(void* const* d_in, const int* in_sizes, int n_in,
                              void* d_out, int out_size, void* d_ws, size_t ws_size,
                              hipStream_t stream) {
    const float* p2  = (const float*)d_in[0];
    const float* p4  = (const float*)d_in[1];
    const float* iw1 = (const float*)d_in[2];
    const float* ib1 = (const float*)d_in[3];
    const float* iw2 = (const float*)d_in[4];
    const float* ib2 = (const float*)d_in[5];
    const float* iw3 = (const float*)d_in[6];
    const float* ib3 = (const float*)d_in[7];
    const float* rw1 = (const float*)d_in[8];
    const float* rb1 = (const float*)d_in[9];
    const float* rw2 = (const float*)d_in[10];
    const float* rb2 = (const float*)d_in[11];
    const float* rw3 = (const float*)d_in[12];
    const float* rb3 = (const float*)d_in[13];
    const float* vw1 = (const float*)d_in[14];
    const float* vb1 = (const float*)d_in[15];
    const float* vw2 = (const float*)d_in[16];
    const float* vb2 = (const float*)d_in[17];
    float* out = (float*)d_out;
    float* ws = (float*)d_ws;
    float* flat = ws + WS_FLAT;
    float* part = ws + WS_PART;
    float* h1   = ws + WS_H1;
    float* h2   = ws + WS_H2;
    float* poly = ws + WS_POLY;

    pool_k<<<256, 256, 0, stream>>>(p4, flat);
    g1a_k<<<256, 512, 0, stream>>>(flat, iw1, part);
    g1b_k<<<64, 256, 0, stream>>>(part, ib1, h1);
    g2_k<<<16, 256, 0, stream>>>(h1, iw2, ib2, h2);
    g3_k<<<32, 256, 0, stream>>>(h2, iw3, ib3, out + 8080, poly);
    for (int s = 0; s < 3; ++s)
        step_k<<<500, 256, 0, stream>>>(p2, rw1, rb1, rw2, rb2, rw3, rb3, poly);
    valid_k<<<80, 128, 0, stream>>>(poly, vw1, vb1, vw2, vb2, out);
}

// Round 2
// 603.856 us; speedup vs baseline: 1.0676x; 1.0676x over previous
//
#include <hip/hip_runtime.h>
#include <math.h>

// Workspace layout (floats)
#define WS_FLAT 0                      // 65536   pooled+flattened p4
#define WS_PART 65536                  // 524288  gemm1 split-K partials (256 x 2048)
#define WS_H1   (65536 + 524288)       // 2048
#define WS_H2   (WS_H1 + 2048)         // 4096
#define WS_POLY (WS_H2 + 4096)         // 8000    current polygons [4][20][50][2]
#define WS_P2T  1048576                // 67108864 floats: p2 transposed to [B,H,W,C]

// ---------------- Kernel 0: transpose p2 [4,256,256x256] CHW -> HWC
// Per block: 64(c) x 64(yx) tile. grid 16384, block 256.
__global__ void __launch_bounds__(256) transpose_k(const float* __restrict__ in,
                                                   float* __restrict__ out) {
    __shared__ float t[64][65];   // t[yx_local][c_local], pad to break bank stride
    int tile = blockIdx.x;        // 0..16383
    int b  = tile >> 12;          // 4
    int ct = (tile >> 10) & 3;    // 4 c-tiles
    int xt = tile & 1023;         // 1024 yx-tiles
    int c0 = ct << 6, yx0 = xt << 6;
    int tid = threadIdx.x;

    // load: lanes sweep yx (contiguous), rows sweep c
    int jv = (tid & 15) << 2;     // yx-local base (float4)
    int i0 = tid >> 4;            // c-local start
    const float* ip = in + (((size_t)(b * 256 + c0)) << 16) + yx0;
    #pragma unroll
    for (int ii = i0; ii < 64; ii += 16) {
        float4 v = *(const float4*)(ip + ((size_t)ii << 16) + jv);
        t[jv + 0][ii] = v.x; t[jv + 1][ii] = v.y;
        t[jv + 2][ii] = v.z; t[jv + 3][ii] = v.w;
    }
    __syncthreads();

    // store: lanes sweep c (contiguous), rows sweep yx
    int iv = (tid & 15) << 2;     // c-local base (float4)
    int j0 = tid >> 4;            // yx-local start
    float* op = out + ((size_t)b << 24) + ((size_t)yx0 << 8) + c0;
    #pragma unroll
    for (int jj = j0; jj < 64; jj += 16) {
        float4 v = make_float4(t[jj][iv], t[jj][iv + 1], t[jj][iv + 2], t[jj][iv + 3]);
        *(float4*)(op + ((size_t)jj << 8) + iv) = v;
    }
}

// ---------------- Kernel 1: AdaptiveAvgPool2d(8) on p4 [4,256,64,64] -> flat [4,16384]
__global__ void pool_k(const float* __restrict__ p4, float* __restrict__ flat) {
    int o = blockIdx.x * blockDim.x + threadIdx.x;   // 65536 outputs
    int b = o >> 14;
    int c = (o >> 6) & 255;
    int ij = o & 63;
    int i = ij >> 3, j = ij & 7;
    const float* base = p4 + (((size_t)(b * 256 + c) * 64 + i * 8) * 64 + j * 8);
    float s = 0.f;
    #pragma unroll
    for (int u = 0; u < 8; ++u) {
        const float4* r = (const float4*)(base + u * 64);
        float4 a = r[0], bb = r[1];
        s += a.x + a.y + a.z + a.w + bb.x + bb.y + bb.z + bb.w;
    }
    flat[o] = s * (1.0f / 64.0f);
}

// ---------------- Kernel 2a: GEMM1 split-K: flat[4,16384] @ iw1[16384,512] -> partials
__global__ void g1a_k(const float* __restrict__ flat, const float* __restrict__ iw1,
                      float* __restrict__ part) {
    __shared__ float sf[4][64];
    int tid = threadIdx.x;              // 0..511
    int kbase = blockIdx.x * 64;
    if (tid < 256) sf[tid >> 6][tid & 63] = flat[(tid >> 6) * 16384 + kbase + (tid & 63)];
    __syncthreads();
    float a0 = 0.f, a1 = 0.f, a2 = 0.f, a3 = 0.f;
    for (int k = 0; k < 64; ++k) {
        float w = iw1[(size_t)(kbase + k) * 512 + tid];
        a0 = fmaf(sf[0][k], w, a0);
        a1 = fmaf(sf[1][k], w, a1);
        a2 = fmaf(sf[2][k], w, a2);
        a3 = fmaf(sf[3][k], w, a3);
    }
    float* pp = part + (size_t)blockIdx.x * 2048;
    pp[tid] = a0; pp[512 + tid] = a1; pp[1024 + tid] = a2; pp[1536 + tid] = a3;
}

// ---------------- Kernel 2b: reduce partials -> h1[2048] (+bias, relu)
__global__ void g1b_k(const float* __restrict__ part, const float* __restrict__ ib1,
                      float* __restrict__ h1) {
    __shared__ float red[8][32];
    int tid = threadIdx.x;
    int cc = tid >> 5, oo = tid & 31;
    int o = blockIdx.x * 32 + oo;
    float s = 0.f;
    for (int i = 0; i < 32; ++i)
        s += part[(size_t)(cc + 8 * i) * 2048 + o];
    red[cc][oo] = s;
    __syncthreads();
    if (cc == 0) {
        float t = 0.f;
        #pragma unroll
        for (int c2 = 0; c2 < 8; ++c2) t += red[c2][oo];
        t += ib1[o & 511];
        h1[o] = fmaxf(t, 0.f);
    }
}

// ---------------- Kernel 3: GEMM2 h1[4,512] @ iw2[512,1024] -> h2[4,1024] (relu)
// grid 64 = 4b x 16 j-tiles(64); block 256 = 64 j x 4 k-chunks(128)
__global__ void g2_k(const float* __restrict__ h1, const float* __restrict__ iw2,
                     const float* __restrict__ ib2, float* __restrict__ h2) {
    __shared__ float sh[512];
    __shared__ float red[4][64];
    int tid = threadIdx.x;
    int b = blockIdx.x >> 4, jt = blockIdx.x & 15;
    sh[tid] = h1[b * 512 + tid];
    sh[tid + 256] = h1[b * 512 + 256 + tid];
    __syncthreads();
    int j = (jt << 6) + (tid & 63);
    int kc = tid >> 6;
    float acc = 0.f;
    for (int k = kc * 128; k < kc * 128 + 128; ++k)
        acc = fmaf(sh[k], iw2[(size_t)k * 1024 + j], acc);
    red[kc][tid & 63] = acc;
    __syncthreads();
    if (kc == 0) {
        float t = red[0][tid] + red[1][tid] + red[2][tid] + red[3][tid] + ib2[j];
        h2[b * 1024 + j] = fmaxf(t, 0.f);
    }
}

// ---------------- Kernel 4: GEMM3 h2[4,1024] @ iw3[1024,2000] -> sigmoid -> init polys
// grid 128 = 4b x 32 j-tiles(64); block 256 = 64 j x 4 k-chunks(256)
__global__ void g3_k(const float* __restrict__ h2, const float* __restrict__ iw3,
                     const float* __restrict__ ib3, float* __restrict__ out_init,
                     float* __restrict__ poly) {
    __shared__ float sh[1024];
    __shared__ float red[4][64];
    int tid = threadIdx.x;
    int b = blockIdx.x >> 5, jt = blockIdx.x & 31;
    const float* h = h2 + b * 1024;
    sh[tid] = h[tid]; sh[tid + 256] = h[tid + 256];
    sh[tid + 512] = h[tid + 512]; sh[tid + 768] = h[tid + 768];
    __syncthreads();
    int j = (jt << 6) + (tid & 63);
    int kc = tid >> 6;
    float acc = 0.f;
    if (j < 2000) {
        for (int k = kc * 256; k < kc * 256 + 256; ++k)
            acc = fmaf(sh[k], iw3[(size_t)k * 2000 + j], acc);
    }
    red[kc][tid & 63] = acc;
    __syncthreads();
    if (kc == 0 && j < 2000) {
        float t = red[0][tid] + red[1][tid] + red[2][tid] + red[3][tid] + ib3[j];
        float s = 1.f / (1.f + expf(-t));
        int o = b * 2000 + j;
        out_init[o] = s;
        poly[o] = s;
    }
}

// ---------------- Kernel 5: one refinement step (HWC gather + MLP + update), 8 pts/block
__global__ void __launch_bounds__(256) step_k(
    const float* __restrict__ p2t,
    const float* __restrict__ rw1, const float* __restrict__ rb1,
    const float* __restrict__ rw2, const float* __restrict__ rb2,
    const float* __restrict__ rw3, const float* __restrict__ rb3,
    float* __restrict__ poly) {
    __shared__ __align__(16) float s_inp[258 * 8];  // [k][p]
    __shared__ __align__(16) float s_r1[256 * 8];   // [j][p]
    __shared__ __align__(16) float s_r2[128 * 8];   // [j][p]
    int tid = threadIdx.x;
    int pt0 = blockIdx.x * 8;
    int b = pt0 / 1000;                 // 1000 % 8 == 0: whole block same batch
    const float* bt = p2t + ((size_t)b << 24);

    // Phase A: bilinear border sampling, lane = channel (coalesced in HWC)
    float val[8];
    #pragma unroll
    for (int pp = 0; pp < 8; ++pp) {
        int pt = pt0 + pp;
        float cx = poly[pt * 2], cy = poly[pt * 2 + 1];
        float ix = fminf(fmaxf(cx * 256.f - 0.5f, 0.f), 255.f);
        float iy = fminf(fmaxf(cy * 256.f - 0.5f, 0.f), 255.f);
        float x0f = floorf(ix), y0f = floorf(iy);
        int x0 = (int)x0f, y0 = (int)y0f;
        int x1 = min(x0 + 1, 255), y1 = min(y0 + 1, 255);
        float wx = ix - x0f, wy = iy - y0f;
        int r0 = (y0 << 16) + (x0 << 8);
        int r1i = (y1 << 16) + (x0 << 8);
        int dx = (x1 - x0) << 8;        // 0 or 256
        float f00 = bt[r0 + tid],  f01 = bt[r0 + dx + tid];
        float f10 = bt[r1i + tid], f11 = bt[r1i + dx + tid];
        float top = f00 * (1.f - wx) + f01 * wx;
        float bot = f10 * (1.f - wx) + f11 * wx;
        val[pp] = top * (1.f - wy) + bot * wy;
    }
    ((float4*)&s_inp[tid * 8])[0] = make_float4(val[0], val[1], val[2], val[3]);
    ((float4*)&s_inp[tid * 8])[1] = make_float4(val[4], val[5], val[6], val[7]);
    if (tid < 16) {  // coords rows 256,257 of inp
        int p = tid >> 1, d = tid & 1;
        s_inp[(256 + d) * 8 + p] = poly[(pt0 + p) * 2 + d];
    }
    __syncthreads();

    // r1 = relu(inp @ rw1 + rb1): thread = column j, 8 accumulators (one/point)
    {
        float bias = rb1[tid];
        float a0 = bias, a1 = bias, a2 = bias, a3 = bias;
        float a4 = bias, a5 = bias, a6 = bias, a7 = bias;
        for (int k = 0; k < 258; ++k) {
            float w = rw1[k * 256 + tid];
            float4 v0 = ((const float4*)&s_inp[k * 8])[0];
            float4 v1 = ((const float4*)&s_inp[k * 8])[1];
            a0 = fmaf(v0.x, w, a0); a1 = fmaf(v0.y, w, a1);
            a2 = fmaf(v0.z, w, a2); a3 = fmaf(v0.w, w, a3);
            a4 = fmaf(v1.x, w, a4); a5 = fmaf(v1.y, w, a5);
            a6 = fmaf(v1.z, w, a6); a7 = fmaf(v1.w, w, a7);
        }
        ((float4*)&s_r1[tid * 8])[0] =
            make_float4(fmaxf(a0, 0.f), fmaxf(a1, 0.f), fmaxf(a2, 0.f), fmaxf(a3, 0.f));
        ((float4*)&s_r1[tid * 8])[1] =
            make_float4(fmaxf(a4, 0.f), fmaxf(a5, 0.f), fmaxf(a6, 0.f), fmaxf(a7, 0.f));
    }
    __syncthreads();

    // r2 = relu(r1 @ rw2 + rb2): thread = (column j in [0,128), point-half ph)
    {
        int j = tid & 127, ph = tid >> 7;
        float bias = rb2[j];
        float c0 = bias, c1 = bias, c2 = bias, c3 = bias;
        for (int k = 0; k < 256; ++k) {
            float w = rw2[k * 128 + j];
            float4 v = ((const float4*)&s_r1[k * 8])[ph];
            c0 = fmaf(v.x, w, c0); c1 = fmaf(v.y, w, c1);
            c2 = fmaf(v.z, w, c2); c3 = fmaf(v.w, w, c3);
        }
        ((float4*)&s_r2[j * 8])[ph] =
            make_float4(fmaxf(c0, 0.f), fmaxf(c1, 0.f), fmaxf(c2, 0.f), fmaxf(c3, 0.f));
    }
    __syncthreads();

    // r3 -> tanh -> scaled clip -> polygon update (16 outputs: 8 pts x 2 dims)
    if (tid < 16) {
        int p = tid >> 1, d = tid & 1;
        float acc = rb3[d];
        for (int k = 0; k < 128; ++k)
            acc = fmaf(s_r2[k * 8 + p], rw3[k * 2 + d], acc);
        float disp = tanhf(acc) * 0.08f;
        disp = fminf(fmaxf(disp, -0.16f), 0.16f);
        int idx = (pt0 + p) * 2 + d;
        float nv = poly[idx] + disp;
        poly[idx] = fminf(fmaxf(nv, 0.f), 1.f);
    }
}

// ---------------- Kernel 6: validity head + final polygon copy to d_out
__global__ void valid_k(const float* __restrict__ poly,
                        const float* __restrict__ vw1, const float* __restrict__ vb1,
                        const float* __restrict__ vw2, const float* __restrict__ vb2,
                        float* __restrict__ out) {
    __shared__ float sp[100];
    __shared__ float sred[2];
    int tid = threadIdx.x;  // 128
    int row = blockIdx.x;   // 80
    if (tid < 100) {
        float v = poly[row * 100 + tid];
        sp[tid] = v;
        out[row * 100 + tid] = v;   // polygons output copy
    }
    __syncthreads();
    float acc = vb1[tid];
    for (int k = 0; k < 100; ++k)
        acc = fmaf(sp[k], vw1[k * 128 + tid], acc);
    float pr = fmaxf(acc, 0.f) * vw2[tid];
    #pragma unroll
    for (int off = 32; off > 0; off >>= 1)
        pr += __shfl_down(pr, off, 64);
    if ((tid & 63) == 0) sred[tid >> 6] = pr;
    __syncthreads();
    if (tid == 0) {
        float s = sred[0] + sred[1] + vb2[0];
        out[8000 + row] = 1.f / (1.f + expf(-s));
    }
}

extern "C" void kernel_launch(void* const* d_in, const int* in_sizes, int n_in,
                              void* d_out, int out_size, void* d_ws, size_t ws_size,
                              hipStream_t stream) {
    const float* p2  = (const float*)d_in[0];
    const float* p4  = (const float*)d_in[1];
    const float* iw1 = (const float*)d_in[2];
    const float* ib1 = (const float*)d_in[3];
    const float* iw2 = (const float*)d_in[4];
    const float* ib2 = (const float*)d_in[5];
    const float* iw3 = (const float*)d_in[6];
    const float* ib3 = (const float*)d_in[7];
    const float* rw1 = (const float*)d_in[8];
    const float* rb1 = (const float*)d_in[9];
    const float* rw2 = (const float*)d_in[10];
    const float* rb2 = (const float*)d_in[11];
    const float* rw3 = (const float*)d_in[12];
    const float* rb3 = (const float*)d_in[13];
    const float* vw1 = (const float*)d_in[14];
    const float* vb1 = (const float*)d_in[15];
    const float* vw2 = (const float*)d_in[16];
    const float* vb2 = (const float*)d_in[17];
    float* out = (float*)d_out;
    float* ws = (float*)d_ws;
    float* flat = ws + WS_FLAT;
    float* part = ws + WS_PART;
    float* h1   = ws + WS_H1;
    float* h2   = ws + WS_H2;
    float* poly = ws + WS_POLY;
    float* p2t  = ws + WS_P2T;

    pool_k<<<256, 256, 0, stream>>>(p4, flat);
    g1a_k<<<256, 512, 0, stream>>>(flat, iw1, part);
    g1b_k<<<64, 256, 0, stream>>>(part, ib1, h1);
    g2_k<<<64, 256, 0, stream>>>(h1, iw2, ib2, h2);
    g3_k<<<128, 256, 0, stream>>>(h2, iw3, ib3, out + 8080, poly);
    transpose_k<<<16384, 256, 0, stream>>>(p2, p2t);   // right before steps: p2t L3-hot
    for (int s = 0; s < 3; ++s)
        step_k<<<500, 256, 0, stream>>>(p2t, rw1, rb1, rw2, rb2, rw3, rb3, poly);
    valid_k<<<80, 128, 0, stream>>>(poly, vw1, vb1, vw2, vb2, out);
}

// Round 3
// 585.029 us; speedup vs baseline: 1.1019x; 1.0322x over previous
//
#include <hip/hip_runtime.h>
#include <hip/hip_fp16.h>
#include <math.h>

// Workspace layout (floats)
#define WS_FLAT 0                      // 65536   pooled+flattened p4
#define WS_PART 65536                  // 524288  gemm1 split-K partials (256 x 2048)
#define WS_H1   (65536 + 524288)       // 2048
#define WS_H2   (WS_H1 + 2048)         // 4096
#define WS_POLY (WS_H2 + 4096)         // 8000    current polygons [4][20][50][2]
#define WS_P2T  1048576                // __half p2t [4][65536 px][256 ch] = 134 MB

// ---------------- Kernel 0: transpose p2 [4,256,256x256] CHW fp32 -> HWC fp16
__global__ void __launch_bounds__(256) transpose_k(const float* __restrict__ in,
                                                   __half* __restrict__ out) {
    __shared__ float t[64][65];   // [px_local][c_local]
    int tile = blockIdx.x;        // 0..16383
    int b  = tile >> 12;
    int ct = (tile >> 10) & 3;
    int xt = tile & 1023;
    int c0 = ct << 6, yx0 = xt << 6;
    int tid = threadIdx.x;

    // load: lanes sweep px (contiguous float4), rows sweep c
    int jv = (tid & 15) << 2;
    int i0 = tid >> 4;
    const float* ip = in + (((size_t)(b * 256 + c0)) << 16) + yx0;
    #pragma unroll
    for (int ii = i0; ii < 64; ii += 16) {
        float4 v = *(const float4*)(ip + ((size_t)ii << 16) + jv);
        t[jv + 0][ii] = v.x; t[jv + 1][ii] = v.y;
        t[jv + 2][ii] = v.z; t[jv + 3][ii] = v.w;
    }
    __syncthreads();

    // store: thread = (c-group tid&7 -> 8 ch, px row tid>>3, +32)
    int cl = (tid & 7) << 3;
    #pragma unroll
    for (int jj = tid >> 3; jj < 64; jj += 32) {
        union { __half h[8]; float4 f; } u;
        #pragma unroll
        for (int q = 0; q < 8; ++q) u.h[q] = __float2half(t[jj][cl + q]);
        *(float4*)(out + ((size_t)b << 24) + ((size_t)(yx0 + jj) << 8) + c0 + cl) = u.f;
    }
}

// ---------------- Kernel 1: AdaptiveAvgPool2d(8) on p4 [4,256,64,64] -> flat [4,16384]
__global__ void pool_k(const float* __restrict__ p4, float* __restrict__ flat) {
    int o = blockIdx.x * blockDim.x + threadIdx.x;
    int b = o >> 14;
    int c = (o >> 6) & 255;
    int ij = o & 63;
    int i = ij >> 3, j = ij & 7;
    const float* base = p4 + (((size_t)(b * 256 + c) * 64 + i * 8) * 64 + j * 8);
    float s = 0.f;
    #pragma unroll
    for (int u = 0; u < 8; ++u) {
        const float4* r = (const float4*)(base + u * 64);
        float4 a = r[0], bb = r[1];
        s += a.x + a.y + a.z + a.w + bb.x + bb.y + bb.z + bb.w;
    }
    flat[o] = s * (1.0f / 64.0f);
}

// ---------------- Kernel 2a: GEMM1 split-K
__global__ void g1a_k(const float* __restrict__ flat, const float* __restrict__ iw1,
                      float* __restrict__ part) {
    __shared__ float sf[4][64];
    int tid = threadIdx.x;
    int kbase = blockIdx.x * 64;
    if (tid < 256) sf[tid >> 6][tid & 63] = flat[(tid >> 6) * 16384 + kbase + (tid & 63)];
    __syncthreads();
    float a0 = 0.f, a1 = 0.f, a2 = 0.f, a3 = 0.f;
    for (int k = 0; k < 64; ++k) {
        float w = iw1[(size_t)(kbase + k) * 512 + tid];
        a0 = fmaf(sf[0][k], w, a0);
        a1 = fmaf(sf[1][k], w, a1);
        a2 = fmaf(sf[2][k], w, a2);
        a3 = fmaf(sf[3][k], w, a3);
    }
    float* pp = part + (size_t)blockIdx.x * 2048;
    pp[tid] = a0; pp[512 + tid] = a1; pp[1024 + tid] = a2; pp[1536 + tid] = a3;
}

// ---------------- Kernel 2b: reduce partials -> h1 (+bias, relu)
__global__ void g1b_k(const float* __restrict__ part, const float* __restrict__ ib1,
                      float* __restrict__ h1) {
    __shared__ float red[8][32];
    int tid = threadIdx.x;
    int cc = tid >> 5, oo = tid & 31;
    int o = blockIdx.x * 32 + oo;
    float s = 0.f;
    for (int i = 0; i < 32; ++i)
        s += part[(size_t)(cc + 8 * i) * 2048 + o];
    red[cc][oo] = s;
    __syncthreads();
    if (cc == 0) {
        float t = 0.f;
        #pragma unroll
        for (int c2 = 0; c2 < 8; ++c2) t += red[c2][oo];
        t += ib1[o & 511];
        h1[o] = fmaxf(t, 0.f);
    }
}

// ---------------- Kernel 3: GEMM2
__global__ void g2_k(const float* __restrict__ h1, const float* __restrict__ iw2,
                     const float* __restrict__ ib2, float* __restrict__ h2) {
    __shared__ float sh[512];
    __shared__ float red[4][64];
    int tid = threadIdx.x;
    int b = blockIdx.x >> 4, jt = blockIdx.x & 15;
    sh[tid] = h1[b * 512 + tid];
    sh[tid + 256] = h1[b * 512 + 256 + tid];
    __syncthreads();
    int j = (jt << 6) + (tid & 63);
    int kc = tid >> 6;
    float acc = 0.f;
    for (int k = kc * 128; k < kc * 128 + 128; ++k)
        acc = fmaf(sh[k], iw2[(size_t)k * 1024 + j], acc);
    red[kc][tid & 63] = acc;
    __syncthreads();
    if (kc == 0) {
        float t = red[0][tid] + red[1][tid] + red[2][tid] + red[3][tid] + ib2[j];
        h2[b * 1024 + j] = fmaxf(t, 0.f);
    }
}

// ---------------- Kernel 4: GEMM3 -> sigmoid -> init polys
__global__ void g3_k(const float* __restrict__ h2, const float* __restrict__ iw3,
                     const float* __restrict__ ib3, float* __restrict__ out_init,
                     float* __restrict__ poly) {
    __shared__ float sh[1024];
    __shared__ float red[4][64];
    int tid = threadIdx.x;
    int b = blockIdx.x >> 5, jt = blockIdx.x & 31;
    const float* h = h2 + b * 1024;
    sh[tid] = h[tid]; sh[tid + 256] = h[tid + 256];
    sh[tid + 512] = h[tid + 512]; sh[tid + 768] = h[tid + 768];
    __syncthreads();
    int j = (jt << 6) + (tid & 63);
    int kc = tid >> 6;
    float acc = 0.f;
    if (j < 2000) {
        for (int k = kc * 256; k < kc * 256 + 256; ++k)
            acc = fmaf(sh[k], iw3[(size_t)k * 2000 + j], acc);
    }
    red[kc][tid & 63] = acc;
    __syncthreads();
    if (kc == 0 && j < 2000) {
        float t = red[0][tid] + red[1][tid] + red[2][tid] + red[3][tid] + ib3[j];
        float s = 1.f / (1.f + expf(-t));
        int o = b * 2000 + j;
        out_init[o] = s;
        poly[o] = s;
    }
}

// ---------------- Kernel 5: refinement step, 16 pts/block, 4x4 register tiles
__global__ void __launch_bounds__(256) step_k(
    const __half* __restrict__ p2th,
    const float* __restrict__ rw1, const float* __restrict__ rb1,
    const float* __restrict__ rw2, const float* __restrict__ rb2,
    const float* __restrict__ rw3, const float* __restrict__ rb3,
    float* __restrict__ poly) {
    __shared__ __align__(16) float s_inp[258 * 16];  // [k][pt]
    __shared__ __align__(16) float s_r1[256 * 16];   // [j][pt]
    __shared__ __align__(16) float s_r2[128 * 16];   // [j][pt]
    int tid = threadIdx.x;
    int pt0 = blockIdx.x * 16;

    // ---- gather: thread = (ch-pair tid&127, point-group tid>>7 -> 8 pts)
    {
        int ch2 = (tid & 127) << 1;
        int pgg = tid >> 7;
        float v0[8], v1[8];
        #pragma unroll
        for (int pp = 0; pp < 8; ++pp) {
            int pt = pt0 + pgg * 8 + pp;
            int b = pt / 1000;
            float cx = poly[pt * 2], cy = poly[pt * 2 + 1];
            float ix = fminf(fmaxf(cx * 256.f - 0.5f, 0.f), 255.f);
            float iy = fminf(fmaxf(cy * 256.f - 0.5f, 0.f), 255.f);
            float x0f = floorf(ix), y0f = floorf(iy);
            int x0 = (int)x0f, y0 = (int)y0f;
            int x1 = min(x0 + 1, 255), y1 = min(y0 + 1, 255);
            float wx = ix - x0f, wy = iy - y0f;
            const __half* bt = p2th + ((size_t)b << 24);
            int r0 = (y0 << 16) + (x0 << 8) + ch2;
            int r1a = (y1 << 16) + (x0 << 8) + ch2;
            int dx = (x1 - x0) << 8;
            float2 f00 = __half22float2(*(const __half2*)(bt + r0));
            float2 f01 = __half22float2(*(const __half2*)(bt + r0 + dx));
            float2 f10 = __half22float2(*(const __half2*)(bt + r1a));
            float2 f11 = __half22float2(*(const __half2*)(bt + r1a + dx));
            float t0 = f00.x + (f01.x - f00.x) * wx;
            float b0 = f10.x + (f11.x - f10.x) * wx;
            float t1 = f00.y + (f01.y - f00.y) * wx;
            float b1 = f10.y + (f11.y - f10.y) * wx;
            v0[pp] = t0 + (b0 - t0) * wy;
            v1[pp] = t1 + (b1 - t1) * wy;
        }
        float* r0p = &s_inp[ch2 * 16 + pgg * 8];
        float* r1p = &s_inp[(ch2 + 1) * 16 + pgg * 8];
        ((float4*)r0p)[0] = make_float4(v0[0], v0[1], v0[2], v0[3]);
        ((float4*)r0p)[1] = make_float4(v0[4], v0[5], v0[6], v0[7]);
        ((float4*)r1p)[0] = make_float4(v1[0], v1[1], v1[2], v1[3]);
        ((float4*)r1p)[1] = make_float4(v1[4], v1[5], v1[6], v1[7]);
        if (tid < 32) {  // coord rows 256,257
            int p = tid >> 1, d = tid & 1;
            s_inp[(256 + d) * 16 + p] = poly[(pt0 + p) * 2 + d];
        }
    }
    __syncthreads();

    // ---- r1: thread = (col-group jc=tid&63 -> 4 cols, pt-group pg=tid>>6 -> 4 pts)
    int jc = tid & 63, pg = tid >> 6;
    {
        float4 bias = *(const float4*)(rb1 + jc * 4);
        float4 acc0 = bias, acc1 = bias, acc2 = bias, acc3 = bias;
        for (int k = 0; k < 258; ++k) {
            float4 a = *(const float4*)&s_inp[k * 16 + pg * 4];
            float4 w = *(const float4*)(rw1 + k * 256 + jc * 4);
            acc0.x = fmaf(a.x, w.x, acc0.x); acc0.y = fmaf(a.x, w.y, acc0.y);
            acc0.z = fmaf(a.x, w.z, acc0.z); acc0.w = fmaf(a.x, w.w, acc0.w);
            acc1.x = fmaf(a.y, w.x, acc1.x); acc1.y = fmaf(a.y, w.y, acc1.y);
            acc1.z = fmaf(a.y, w.z, acc1.z); acc1.w = fmaf(a.y, w.w, acc1.w);
            acc2.x = fmaf(a.z, w.x, acc2.x); acc2.y = fmaf(a.z, w.y, acc2.y);
            acc2.z = fmaf(a.z, w.z, acc2.z); acc2.w = fmaf(a.z, w.w, acc2.w);
            acc3.x = fmaf(a.w, w.x, acc3.x); acc3.y = fmaf(a.w, w.y, acc3.y);
            acc3.z = fmaf(a.w, w.z, acc3.z); acc3.w = fmaf(a.w, w.w, acc3.w);
        }
        acc0.x = fmaxf(acc0.x, 0.f); acc0.y = fmaxf(acc0.y, 0.f);
        acc0.z = fmaxf(acc0.z, 0.f); acc0.w = fmaxf(acc0.w, 0.f);
        acc1.x = fmaxf(acc1.x, 0.f); acc1.y = fmaxf(acc1.y, 0.f);
        acc1.z = fmaxf(acc1.z, 0.f); acc1.w = fmaxf(acc1.w, 0.f);
        acc2.x = fmaxf(acc2.x, 0.f); acc2.y = fmaxf(acc2.y, 0.f);
        acc2.z = fmaxf(acc2.z, 0.f); acc2.w = fmaxf(acc2.w, 0.f);
        acc3.x = fmaxf(acc3.x, 0.f); acc3.y = fmaxf(acc3.y, 0.f);
        acc3.z = fmaxf(acc3.z, 0.f); acc3.w = fmaxf(acc3.w, 0.f);
        // store [j][pt]: row jc*4+c gets (acc0[c],acc1[c],acc2[c],acc3[c])
        *(float4*)&s_r1[(jc * 4 + 0) * 16 + pg * 4] = make_float4(acc0.x, acc1.x, acc2.x, acc3.x);
        *(float4*)&s_r1[(jc * 4 + 1) * 16 + pg * 4] = make_float4(acc0.y, acc1.y, acc2.y, acc3.y);
        *(float4*)&s_r1[(jc * 4 + 2) * 16 + pg * 4] = make_float4(acc0.z, acc1.z, acc2.z, acc3.z);
        *(float4*)&s_r1[(jc * 4 + 3) * 16 + pg * 4] = make_float4(acc0.w, acc1.w, acc2.w, acc3.w);
    }
    __syncthreads();

    // ---- r2: thread = (2 cols jc*2, 4 pts pg), k=256
    {
        float2 bias = *(const float2*)(rb2 + jc * 2);
        float2 d0 = bias, d1 = bias, d2 = bias, d3 = bias;
        for (int k = 0; k < 256; ++k) {
            float4 a = *(const float4*)&s_r1[k * 16 + pg * 4];
            float2 w = *(const float2*)(rw2 + k * 128 + jc * 2);
            d0.x = fmaf(a.x, w.x, d0.x); d0.y = fmaf(a.x, w.y, d0.y);
            d1.x = fmaf(a.y, w.x, d1.x); d1.y = fmaf(a.y, w.y, d1.y);
            d2.x = fmaf(a.z, w.x, d2.x); d2.y = fmaf(a.z, w.y, d2.y);
            d3.x = fmaf(a.w, w.x, d3.x); d3.y = fmaf(a.w, w.y, d3.y);
        }
        d0.x = fmaxf(d0.x, 0.f); d0.y = fmaxf(d0.y, 0.f);
        d1.x = fmaxf(d1.x, 0.f); d1.y = fmaxf(d1.y, 0.f);
        d2.x = fmaxf(d2.x, 0.f); d2.y = fmaxf(d2.y, 0.f);
        d3.x = fmaxf(d3.x, 0.f); d3.y = fmaxf(d3.y, 0.f);
        *(float4*)&s_r2[(jc * 2 + 0) * 16 + pg * 4] = make_float4(d0.x, d1.x, d2.x, d3.x);
        *(float4*)&s_r2[(jc * 2 + 1) * 16 + pg * 4] = make_float4(d0.y, d1.y, d2.y, d3.y);
    }
    __syncthreads();

    // ---- r3 -> tanh -> scaled clip -> polygon update (32 outputs)
    if (tid < 32) {
        int p = tid >> 1, d = tid & 1;
        float acc = rb3[d];
        for (int k = 0; k < 128; ++k)
            acc = fmaf(s_r2[k * 16 + p], rw3[k * 2 + d], acc);
        float disp = tanhf(acc) * 0.08f;
        disp = fminf(fmaxf(disp, -0.16f), 0.16f);
        int idx = (pt0 + p) * 2 + d;
        float nv = poly[idx] + disp;
        poly[idx] = fminf(fmaxf(nv, 0.f), 1.f);
    }
}

// ---------------- Kernel 6: validity head + final polygon copy
__global__ void valid_k(const float* __restrict__ poly,
                        const float* __restrict__ vw1, const float* __restrict__ vb1,
                        const float* __restrict__ vw2, const float* __restrict__ vb2,
                        float* __restrict__ out) {
    __shared__ float sp[100];
    __shared__ float sred[2];
    int tid = threadIdx.x;  // 128
    int row = blockIdx.x;   // 80
    if (tid < 100) {
        float v = poly[row * 100 + tid];
        sp[tid] = v;
        out[row * 100 + tid] = v;
    }
    __syncthreads();
    float acc = vb1[tid];
    for (int k = 0; k < 100; ++k)
        acc = fmaf(sp[k], vw1[k * 128 + tid], acc);
    float pr = fmaxf(acc, 0.f) * vw2[tid];
    #pragma unroll
    for (int off = 32; off > 0; off >>= 1)
        pr += __shfl_down(pr, off, 64);
    if ((tid & 63) == 0) sred[tid >> 6] = pr;
    __syncthreads();
    if (tid == 0) {
        float s = sred[0] + sred[1] + vb2[0];
        out[8000 + row] = 1.f / (1.f + expf(-s));
    }
}

extern "C" void kernel_launch(void* const* d_in, const int* in_sizes, int n_in,
                              void* d_out, int out_size, void* d_ws, size_t ws_size,
                              hipStream_t stream) {
    const float* p2  = (const float*)d_in[0];
    const float* p4  = (const float*)d_in[1];
    const float* iw1 = (const float*)d_in[2];
    const float* ib1 = (const float*)d_in[3];
    const float* iw2 = (const float*)d_in[4];
    const float* ib2 = (const float*)d_in[5];
    const float* iw3 = (const float*)d_in[6];
    const float* ib3 = (const float*)d_in[7];
    const float* rw1 = (const float*)d_in[8];
    const float* rb1 = (const float*)d_in[9];
    const float* rw2 = (const float*)d_in[10];
    const float* rb2 = (const float*)d_in[11];
    const float* rw3 = (const float*)d_in[12];
    const float* rb3 = (const float*)d_in[13];
    const float* vw1 = (const float*)d_in[14];
    const float* vb1 = (const float*)d_in[15];
    const float* vw2 = (const float*)d_in[16];
    const float* vb2 = (const float*)d_in[17];
    float* out = (float*)d_out;
    float* ws = (float*)d_ws;
    float* flat = ws + WS_FLAT;
    float* part = ws + WS_PART;
    float* h1   = ws + WS_H1;
    float* h2   = ws + WS_H2;
    float* poly = ws + WS_POLY;
    __half* p2th = (__half*)(ws + WS_P2T);

    pool_k<<<256, 256, 0, stream>>>(p4, flat);
    g1a_k<<<256, 512, 0, stream>>>(flat, iw1, part);
    g1b_k<<<64, 256, 0, stream>>>(part, ib1, h1);
    g2_k<<<64, 256, 0, stream>>>(h1, iw2, ib2, h2);
    g3_k<<<128, 256, 0, stream>>>(h2, iw3, ib3, out + 8080, poly);
    transpose_k<<<16384, 256, 0, stream>>>(p2, p2th);  // fp16 HWC, L3-resident
    for (int s = 0; s < 3; ++s)
        step_k<<<250, 256, 0, stream>>>(p2th, rw1, rb1, rw2, rb2, rw3, rb3, poly);
    valid_k<<<80, 128, 0, stream>>>(poly, vw1, vb1, vw2, vb2, out);
}